// Round 9
// baseline (89.712 us; speedup 1.0000x reference)
//
#include <hip/hip_runtime.h>

#define S_TOTAL (512 * 512)     // 262144
#define BATCH 64
#define KTOT2 16384             // 128 ty * 128 j  (fully folded K)
#define NKC 64                  // k-chunks (256 k each)

typedef float vfloat4 __attribute__((ext_vector_type(4)));
typedef float vfloat2 __attribute__((ext_vector_type(2)));

// ds_swizzle xor helpers (imm must be literal). BitMode: (xor<<10)|0x1f.
__device__ __forceinline__ float swz_x1(float v) {
    return __int_as_float(__builtin_amdgcn_ds_swizzle(__float_as_int(v), 0x041F));
}
__device__ __forceinline__ float swz_x2(float v) {
    return __int_as_float(__builtin_amdgcn_ds_swizzle(__float_as_int(v), 0x081F));
}
__device__ __forceinline__ float swz_x4(float v) {
    return __int_as_float(__builtin_amdgcn_ds_swizzle(__float_as_int(v), 0x101F));
}
__device__ __forceinline__ float swz_x8(float v) {
    return __int_as_float(__builtin_amdgcn_ds_swizzle(__float_as_int(v), 0x201F));
}

// ---------------------------------------------------------------------------
// K1 (fully fused): A,x -> za partials.  Block = (kc 0..63, nh 0..1).
// Phase 1: x-fold straight from global (coalesced 3-window reads) for the
//   block's 10 nr x 12 y rows -> b1loc (zero-pad y outside [0,512)).
// Phase 2: y-fold -> b2loc[10][256] (= B2 slice for this k-chunk).
// Phase 3: R7's proven dot + halving-exchange tree -> partial[kc][b*20+nr].
// ---------------------------------------------------------------------------
__global__ __launch_bounds__(512) void fused_za_kernel(
    const float* __restrict__ x,      // (64, 16384)
    const float* __restrict__ A,      // (20, 512, 512)
    float* __restrict__ partial)      // (64, 1280) elem b*20+nr
{
    __shared__ float b1loc[10][12][128];  // 60 KB
    __shared__ float b2loc[10][256];      // 10 KB

    const int t  = threadIdx.x;
    const int kc = blockIdx.x >> 1;   // k-chunk: ty in {2kc, 2kc+1}
    const int nh = blockIdx.x & 1;    // nr-half
    const int y0 = 8 * kc - 2;        // global y of local row 0

    // ---- phase 1: x-fold (b1) straight from global
#pragma unroll
    for (int i = t; i < 10 * 12 * 128; i += 512) {
        const int nrl = i / (12 * 128);
        const int rem = i - nrl * (12 * 128);
        const int rl  = rem >> 7;
        const int j   = rem & 127;
        const int y   = y0 + rl;
        float s = 0.0f;
        if (y >= 0 && y < 512) {
            const float* Ay = A + ((size_t)(nh * 10 + nrl) * 512 + y) * 512;
            const int base = 4 * j;
            const vfloat4 m0 = *(const vfloat4*)(Ay + max(base - 4, 0));
            const vfloat4 m1 = *(const vfloat4*)(Ay + base);
            const vfloat4 m2 = *(const vfloat4*)(Ay + min(base + 4, 508));
            // window 4j-2..4j+5 = m0.z, m0.w, m1.xyzw, m2.x, m2.y
            float e0 = m0.z, e1 = m0.w, e6 = m2.x, e7 = m2.y;
            if (j == 0)   { e0 = 0.0f; e1 = 0.0f; }
            if (j == 127) { e6 = 0.0f; e7 = 0.0f; }
            s = 0.125f * e0 + 0.375f * e1
              + 0.625f * m1.x + 0.875f * m1.y
              + 0.875f * m1.z + 0.625f * m1.w
              + 0.375f * e6 + 0.125f * e7;
            if (j == 0)   s += 0.375f * Ay[0]   + 0.125f * Ay[1];
            if (j == 127) s += 0.125f * Ay[510] + 0.375f * Ay[511];
        }
        b1loc[nrl][rl][j] = s;
    }
    __syncthreads();

    // ---- phase 2: y-fold -> b2loc (flat kl = tyl*128 + j)
    const float w[8] = {0.125f, 0.375f, 0.625f, 0.875f,
                        0.875f, 0.625f, 0.375f, 0.125f};
#pragma unroll
    for (int i = t; i < 10 * 256; i += 512) {
        const int nrl = i >> 8;
        const int kl  = i & 255;
        const int tyl = kl >> 7;
        const int j   = kl & 127;
        const int ty  = 2 * kc + tyl;
        float s = 0.0f;
#pragma unroll
        for (int p = 0; p < 8; ++p)
            s = fmaf(w[p], b1loc[nrl][4 * tyl + p][j], s);
        if (ty == 0)   s += 0.375f * b1loc[nrl][2][j] + 0.125f * b1loc[nrl][3][j]; // y=0,1
        if (ty == 127) s += 0.125f * b1loc[nrl][8][j] + 0.375f * b1loc[nrl][9][j]; // y=510,511
        b2loc[nrl][kl] = s;
    }
    __syncthreads();

    // ---- phase 3: dot + tree (identical to proven R7 structure, ch == nh)
    const int wv   = t >> 6;
    const int lane = t & 63;
    const int b0   = wv * 8;
    const size_t kbase = (size_t)kc * 256 + 4 * lane;

    vfloat4 xv[8];
#pragma unroll
    for (int bi = 0; bi < 8; ++bi)
        xv[bi] = *(const vfloat4*)(x + (size_t)(b0 + bi) * KTOT2 + kbase);

    const int lane1 = lane & 1, lane2 = lane & 2, lane4 = lane & 4, lane8 = lane & 8;

    float acc[16][5];
#pragma unroll
    for (int v = 0; v < 16; ++v)
#pragma unroll
        for (int tt = 0; tt < 5; ++tt) acc[v][tt] = 0.0f;

#pragma unroll
    for (int tt = 0; tt < 5; ++tt)
#pragma unroll
        for (int par = 0; par < 2; ++par) {
            const vfloat4 bq = *(const vfloat4*)&b2loc[2 * tt + par][4 * lane];
#pragma unroll
            for (int bi = 0; bi < 8; ++bi) {
                acc[bi * 2 + par][tt] =
                    fmaf(bq.x, xv[bi].x, fmaf(bq.y, xv[bi].y,
                    fmaf(bq.z, xv[bi].z, fmaf(bq.w, xv[bi].w,
                         acc[bi * 2 + par][tt]))));
            }
        }

    float s1[8][5];
#pragma unroll
    for (int v = 0; v < 8; ++v)
#pragma unroll
        for (int tt = 0; tt < 5; ++tt) {
            const float u = acc[v][tt], h = acc[v + 8][tt];
            s1[v][tt] = (lane1 ? h : u) + swz_x1(lane1 ? u : h);
        }
    float s2[4][5];
#pragma unroll
    for (int v = 0; v < 4; ++v)
#pragma unroll
        for (int tt = 0; tt < 5; ++tt) {
            const float u = s1[v][tt], h = s1[v + 4][tt];
            s2[v][tt] = (lane2 ? h : u) + swz_x2(lane2 ? u : h);
        }
    float s3[2][5];
#pragma unroll
    for (int v = 0; v < 2; ++v)
#pragma unroll
        for (int tt = 0; tt < 5; ++tt) {
            const float u = s2[v][tt], h = s2[v + 2][tt];
            s3[v][tt] = (lane4 ? h : u) + swz_x4(lane4 ? u : h);
        }
    float s4[5];
#pragma unroll
    for (int tt = 0; tt < 5; ++tt) {
        const float u = s3[0][tt], h = s3[1][tt];
        s4[tt] = (lane8 ? h : u) + swz_x8(lane8 ? u : h);
    }
#pragma unroll
    for (int tt = 0; tt < 5; ++tt) {
        s4[tt] += __shfl_xor(s4[tt], 16, 64);
        s4[tt] += __shfl_xor(s4[tt], 32, 64);
    }

    if (lane < 16) {
        const int m = ((lane & 1) << 3) | ((lane & 2) << 1) |
                      ((lane & 4) >> 1) | ((lane & 8) >> 3);
        float* dst = partial + (size_t)kc * 1280 +
                     (b0 + (m >> 1)) * 20 + nh * 10 + (m & 1);
#pragma unroll
        for (int tt = 0; tt < 5; ++tt) dst[2 * tt] = s4[tt];
    }
}

// ---------------------------------------------------------------------------
// K2: per-block redundant za-reduce (64 partials, L2-hot, coalesced) +
// z recurrence + out = z*C^T + bias. 512 blocks x 256 thr, thread owns an
// s-pair, full batch per block (C read exactly once). float2 NT stores.
// ---------------------------------------------------------------------------
__global__ __launch_bounds__(256) void out_kernel(
    const float* __restrict__ C,       // (S,4)
    const float* __restrict__ bias,    // (S,)
    const float* __restrict__ partial, // (64, 1280)
    float* __restrict__ out)           // (64,S)
{
    __shared__ float za_sh[1280];
    __shared__ float zs[256];
    const int t = threadIdx.x;

    // reduce 64 k-chunk partials (coalesced: c = q*256 + t)
#pragma unroll
    for (int q = 0; q < 5; ++q) {
        const int c = q * 256 + t;
        float a0 = 0, a1 = 0, a2 = 0, a3 = 0;
        for (int r = 0; r < NKC; r += 4) {
            a0 += partial[(size_t)(r + 0) * 1280 + c];
            a1 += partial[(size_t)(r + 1) * 1280 + c];
            a2 += partial[(size_t)(r + 2) * 1280 + c];
            a3 += partial[(size_t)(r + 3) * 1280 + c];
        }
        za_sh[c] = (a0 + a1) + (a2 + a3);
    }
    __syncthreads();
    if (t < 64) {
#pragma unroll
        for (int r = 0; r < 4; ++r) {
            float zv = za_sh[t * 20 + r];               // n = 0
#pragma unroll
            for (int n = 1; n < 5; ++n)
                zv *= (1.0f + za_sh[t * 20 + n * 4 + r]);
            zs[t * 4 + r] = zv;
        }
    }
    __syncthreads();

    const int s0 = (blockIdx.x * 256 + t) * 2;
    const vfloat4 c0 = *(const vfloat4*)(C + (size_t)s0 * 4);
    const vfloat4 c1 = *(const vfloat4*)(C + (size_t)s0 * 4 + 4);
    const vfloat2 bv = *(const vfloat2*)(bias + s0);

#pragma unroll 8
    for (int bb = 0; bb < BATCH; ++bb) {
        const float z0 = zs[bb * 4 + 0], z1 = zs[bb * 4 + 1];
        const float z2 = zs[bb * 4 + 2], z3 = zs[bb * 4 + 3];
        vfloat2 o;
        o.x = fmaf(z0, c0.x, fmaf(z1, c0.y, fmaf(z2, c0.z, fmaf(z3, c0.w, bv.x))));
        o.y = fmaf(z0, c1.x, fmaf(z1, c1.y, fmaf(z2, c1.z, fmaf(z3, c1.w, bv.y))));
        __builtin_nontemporal_store(o, (vfloat2*)(out + (size_t)bb * S_TOTAL + s0));
    }
}

// ---------------------------------------------------------------------------
extern "C" void kernel_launch(void* const* d_in, const int* in_sizes, int n_in,
                              void* d_out, int out_size, void* d_ws, size_t ws_size,
                              hipStream_t stream)
{
    const float* x    = (const float*)d_in[0];
    const float* A    = (const float*)d_in[1];
    const float* C    = (const float*)d_in[2];
    const float* bias = (const float*)d_in[3];
    float* out = (float*)d_out;

    float* partial = (float*)d_ws;                       // 64*1280 floats

    fused_za_kernel<<<NKC * 2, 512, 0, stream>>>(x, A, partial);
    out_kernel<<<512, 256, 0, stream>>>(C, bias, partial, out);
}

// Round 10
// 48.277 us; speedup vs baseline: 1.8583x; 1.8583x over previous
//
#include <hip/hip_runtime.h>

#define S_TOTAL (512 * 512)     // 262144
#define BATCH 64
#define KTOT2 16384             // 128 ty * 128 j  (fully folded K)
#define NKC 64                  // k-chunks (256 k each)

typedef float vfloat4 __attribute__((ext_vector_type(4)));
typedef float vfloat2 __attribute__((ext_vector_type(2)));

// ds_swizzle xor helpers (imm must be literal). BitMode: (xor<<10)|0x1f.
__device__ __forceinline__ float swz_x1(float v) {
    return __int_as_float(__builtin_amdgcn_ds_swizzle(__float_as_int(v), 0x041F));
}
__device__ __forceinline__ float swz_x2(float v) {
    return __int_as_float(__builtin_amdgcn_ds_swizzle(__float_as_int(v), 0x081F));
}
__device__ __forceinline__ float swz_x4(float v) {
    return __int_as_float(__builtin_amdgcn_ds_swizzle(__float_as_int(v), 0x101F));
}
__device__ __forceinline__ float swz_x8(float v) {
    return __int_as_float(__builtin_amdgcn_ds_swizzle(__float_as_int(v), 0x201F));
}

// ---------------------------------------------------------------------------
// K1 (fused, unchanged from R9 — proven): A,x -> za partials.
// Block = (kc 0..63, nh 0..1). x-fold straight from global, y-fold in LDS,
// then dot + halving-exchange tree -> partial[kc][b*20+nr].
// ---------------------------------------------------------------------------
__global__ __launch_bounds__(512) void fused_za_kernel(
    const float* __restrict__ x,      // (64, 16384)
    const float* __restrict__ A,      // (20, 512, 512)
    float* __restrict__ partial)      // (64, 1280) elem b*20+nr
{
    __shared__ float b1loc[10][12][128];  // 60 KB
    __shared__ float b2loc[10][256];      // 10 KB

    const int t  = threadIdx.x;
    const int kc = blockIdx.x >> 1;   // k-chunk: ty in {2kc, 2kc+1}
    const int nh = blockIdx.x & 1;    // nr-half
    const int y0 = 8 * kc - 2;        // global y of local row 0

    // ---- phase 1: x-fold (b1) straight from global
#pragma unroll
    for (int i = t; i < 10 * 12 * 128; i += 512) {
        const int nrl = i / (12 * 128);
        const int rem = i - nrl * (12 * 128);
        const int rl  = rem >> 7;
        const int j   = rem & 127;
        const int y   = y0 + rl;
        float s = 0.0f;
        if (y >= 0 && y < 512) {
            const float* Ay = A + ((size_t)(nh * 10 + nrl) * 512 + y) * 512;
            const int base = 4 * j;
            const vfloat4 m0 = *(const vfloat4*)(Ay + max(base - 4, 0));
            const vfloat4 m1 = *(const vfloat4*)(Ay + base);
            const vfloat4 m2 = *(const vfloat4*)(Ay + min(base + 4, 508));
            float e0 = m0.z, e1 = m0.w, e6 = m2.x, e7 = m2.y;
            if (j == 0)   { e0 = 0.0f; e1 = 0.0f; }
            if (j == 127) { e6 = 0.0f; e7 = 0.0f; }
            s = 0.125f * e0 + 0.375f * e1
              + 0.625f * m1.x + 0.875f * m1.y
              + 0.875f * m1.z + 0.625f * m1.w
              + 0.375f * e6 + 0.125f * e7;
            if (j == 0)   s += 0.375f * Ay[0]   + 0.125f * Ay[1];
            if (j == 127) s += 0.125f * Ay[510] + 0.375f * Ay[511];
        }
        b1loc[nrl][rl][j] = s;
    }
    __syncthreads();

    // ---- phase 2: y-fold -> b2loc (flat kl = tyl*128 + j)
    const float w[8] = {0.125f, 0.375f, 0.625f, 0.875f,
                        0.875f, 0.625f, 0.375f, 0.125f};
#pragma unroll
    for (int i = t; i < 10 * 256; i += 512) {
        const int nrl = i >> 8;
        const int kl  = i & 255;
        const int tyl = kl >> 7;
        const int j   = kl & 127;
        const int ty  = 2 * kc + tyl;
        float s = 0.0f;
#pragma unroll
        for (int p = 0; p < 8; ++p)
            s = fmaf(w[p], b1loc[nrl][4 * tyl + p][j], s);
        if (ty == 0)   s += 0.375f * b1loc[nrl][2][j] + 0.125f * b1loc[nrl][3][j];
        if (ty == 127) s += 0.125f * b1loc[nrl][8][j] + 0.375f * b1loc[nrl][9][j];
        b2loc[nrl][kl] = s;
    }
    __syncthreads();

    // ---- phase 3: dot + tree
    const int wv   = t >> 6;
    const int lane = t & 63;
    const int b0   = wv * 8;
    const size_t kbase = (size_t)kc * 256 + 4 * lane;

    vfloat4 xv[8];
#pragma unroll
    for (int bi = 0; bi < 8; ++bi)
        xv[bi] = *(const vfloat4*)(x + (size_t)(b0 + bi) * KTOT2 + kbase);

    const int lane1 = lane & 1, lane2 = lane & 2, lane4 = lane & 4, lane8 = lane & 8;

    float acc[16][5];
#pragma unroll
    for (int v = 0; v < 16; ++v)
#pragma unroll
        for (int tt = 0; tt < 5; ++tt) acc[v][tt] = 0.0f;

#pragma unroll
    for (int tt = 0; tt < 5; ++tt)
#pragma unroll
        for (int par = 0; par < 2; ++par) {
            const vfloat4 bq = *(const vfloat4*)&b2loc[2 * tt + par][4 * lane];
#pragma unroll
            for (int bi = 0; bi < 8; ++bi) {
                acc[bi * 2 + par][tt] =
                    fmaf(bq.x, xv[bi].x, fmaf(bq.y, xv[bi].y,
                    fmaf(bq.z, xv[bi].z, fmaf(bq.w, xv[bi].w,
                         acc[bi * 2 + par][tt]))));
            }
        }

    float s1[8][5];
#pragma unroll
    for (int v = 0; v < 8; ++v)
#pragma unroll
        for (int tt = 0; tt < 5; ++tt) {
            const float u = acc[v][tt], h = acc[v + 8][tt];
            s1[v][tt] = (lane1 ? h : u) + swz_x1(lane1 ? u : h);
        }
    float s2[4][5];
#pragma unroll
    for (int v = 0; v < 4; ++v)
#pragma unroll
        for (int tt = 0; tt < 5; ++tt) {
            const float u = s1[v][tt], h = s1[v + 4][tt];
            s2[v][tt] = (lane2 ? h : u) + swz_x2(lane2 ? u : h);
        }
    float s3[2][5];
#pragma unroll
    for (int v = 0; v < 2; ++v)
#pragma unroll
        for (int tt = 0; tt < 5; ++tt) {
            const float u = s2[v][tt], h = s2[v + 2][tt];
            s3[v][tt] = (lane4 ? h : u) + swz_x4(lane4 ? u : h);
        }
    float s4[5];
#pragma unroll
    for (int tt = 0; tt < 5; ++tt) {
        const float u = s3[0][tt], h = s3[1][tt];
        s4[tt] = (lane8 ? h : u) + swz_x8(lane8 ? u : h);
    }
#pragma unroll
    for (int tt = 0; tt < 5; ++tt) {
        s4[tt] += __shfl_xor(s4[tt], 16, 64);
        s4[tt] += __shfl_xor(s4[tt], 32, 64);
    }

    if (lane < 16) {
        const int m = ((lane & 1) << 3) | ((lane & 2) << 1) |
                      ((lane & 4) >> 1) | ((lane & 8) >> 3);
        float* dst = partial + (size_t)kc * 1280 +
                     (b0 + (m >> 1)) * 20 + nh * 10 + (m & 1);
#pragma unroll
        for (int tt = 0; tt < 5; ++tt) dst[2 * tt] = s4[tt];
    }
}

// ---------------------------------------------------------------------------
// K2: single-block za-reduce (327 KB, once) + z recurrence -> zg[256].
// ---------------------------------------------------------------------------
__global__ __launch_bounds__(1024) void za_reduce_z_kernel(
    const float* __restrict__ partial,   // (64, 1280)
    float* __restrict__ zg)              // (256,) z[b*4+r]
{
    __shared__ float za_sh[1280];
    const int t = threadIdx.x;
    if (t < 640) {
        const int c = 2 * t;
        float a0 = 0, a1 = 0, b0 = 0, b1 = 0;
        for (int r = 0; r < NKC; r += 2) {
            const vfloat2 p0 = *(const vfloat2*)(partial + (size_t)r * 1280 + c);
            const vfloat2 p1 = *(const vfloat2*)(partial + (size_t)(r + 1) * 1280 + c);
            a0 += p0.x; a1 += p0.y;
            b0 += p1.x; b1 += p1.y;
        }
        za_sh[c]     = a0 + b0;
        za_sh[c + 1] = a1 + b1;
    }
    __syncthreads();
    if (t < 64) {
#pragma unroll
        for (int r = 0; r < 4; ++r) {
            float zv = za_sh[t * 20 + r];               // n = 0
#pragma unroll
            for (int n = 1; n < 5; ++n)
                zv *= (1.0f + za_sh[t * 20 + n * 4 + r]);
            zg[t * 4 + r] = zv;
        }
    }
}

// ---------------------------------------------------------------------------
// K3: out = z*C^T + bias. 512 blocks = 256 s-chunks x 2 batch-halves.
// Thread owns 4 consecutive s; float4 NT stores (16 B/lane).
// ---------------------------------------------------------------------------
__global__ __launch_bounds__(256) void out_kernel(
    const float* __restrict__ C,      // (S,4)
    const float* __restrict__ bias,   // (S,)
    const float* __restrict__ zg,     // (256,) z[b*4+r]
    float* __restrict__ out)          // (64,S)
{
    __shared__ float zs[256];
    const int t = threadIdx.x;
    zs[t] = zg[t];
    __syncthreads();

    const int sb = blockIdx.x >> 1;
    const int bh = blockIdx.x & 1;
    const int s0 = (sb * 256 + t) * 4;
    const vfloat4 c0 = *(const vfloat4*)(C + (size_t)s0 * 4);
    const vfloat4 c1 = *(const vfloat4*)(C + (size_t)s0 * 4 + 4);
    const vfloat4 c2 = *(const vfloat4*)(C + (size_t)s0 * 4 + 8);
    const vfloat4 c3 = *(const vfloat4*)(C + (size_t)s0 * 4 + 12);
    const vfloat4 bv = *(const vfloat4*)(bias + s0);

#pragma unroll 8
    for (int bb = bh * 32; bb < bh * 32 + 32; ++bb) {
        const float z0 = zs[bb * 4 + 0], z1 = zs[bb * 4 + 1];
        const float z2 = zs[bb * 4 + 2], z3 = zs[bb * 4 + 3];
        vfloat4 o;
        o.x = fmaf(z0, c0.x, fmaf(z1, c0.y, fmaf(z2, c0.z, fmaf(z3, c0.w, bv.x))));
        o.y = fmaf(z0, c1.x, fmaf(z1, c1.y, fmaf(z2, c1.z, fmaf(z3, c1.w, bv.y))));
        o.z = fmaf(z0, c2.x, fmaf(z1, c2.y, fmaf(z2, c2.z, fmaf(z3, c2.w, bv.z))));
        o.w = fmaf(z0, c3.x, fmaf(z1, c3.y, fmaf(z2, c3.z, fmaf(z3, c3.w, bv.w))));
        __builtin_nontemporal_store(o, (vfloat4*)(out + (size_t)bb * S_TOTAL + s0));
    }
}

// ---------------------------------------------------------------------------
extern "C" void kernel_launch(void* const* d_in, const int* in_sizes, int n_in,
                              void* d_out, int out_size, void* d_ws, size_t ws_size,
                              hipStream_t stream)
{
    const float* x    = (const float*)d_in[0];
    const float* A    = (const float*)d_in[1];
    const float* C    = (const float*)d_in[2];
    const float* bias = (const float*)d_in[3];
    float* out = (float*)d_out;

    float* partial = (float*)d_ws;                       // 64*1280 floats
    float* zg      = partial + (size_t)NKC * 1280;       // 256 floats

    fused_za_kernel<<<NKC * 2, 512, 0, stream>>>(x, A, partial);
    za_reduce_z_kernel<<<1, 1024, 0, stream>>>(partial, zg);
    out_kernel<<<512, 256, 0, stream>>>(C, bias, zg, out);
}

// Round 11
// 34.934 us; speedup vs baseline: 2.5680x; 1.3820x over previous
//
#include <hip/hip_runtime.h>

#define S_TOTAL (512 * 512)     // 262144
#define BATCH 64
#define KTOT2 16384             // 128 ty * 128 j  (fully folded K)
#define NKC 64                  // k-chunks (256 k each)

typedef float vfloat4 __attribute__((ext_vector_type(4)));

// ds_swizzle xor helpers (imm must be literal). BitMode: (xor<<10)|0x1f.
__device__ __forceinline__ float swz_x1(float v) {
    return __int_as_float(__builtin_amdgcn_ds_swizzle(__float_as_int(v), 0x041F));
}
__device__ __forceinline__ float swz_x2(float v) {
    return __int_as_float(__builtin_amdgcn_ds_swizzle(__float_as_int(v), 0x081F));
}
__device__ __forceinline__ float swz_x4(float v) {
    return __int_as_float(__builtin_amdgcn_ds_swizzle(__float_as_int(v), 0x101F));
}
__device__ __forceinline__ float swz_x8(float v) {
    return __int_as_float(__builtin_amdgcn_ds_swizzle(__float_as_int(v), 0x201F));
}

// ---------------------------------------------------------------------------
// K1: A -> B2 (both bilinear adjoints folded). 640 blocks x 256 thr.
// x-fold straight from global (coalesced 3-window float4 reads, L1-overlap);
// only 10 KB LDS -> high occupancy. Proven logic (R8-R10, absmax 0.5).
// ---------------------------------------------------------------------------
__global__ __launch_bounds__(256) void adjxy_kernel(
    const float* __restrict__ A,      // (20, 512, 512)
    float* __restrict__ B2)           // (20, 128, 128)
{
    __shared__ float b1loc[20][128];  // 10 KB

    const int t  = threadIdx.x;
    const int nr = blockIdx.x >> 5;   // 0..19
    const int tc = blockIdx.x & 31;   // ty-chunk 0..31
    const int y0 = 16 * tc - 2;       // global y of local row 0

    const float* An = A + (size_t)nr * S_TOTAL;

#pragma unroll
    for (int i = t; i < 20 * 128; i += 256) {
        const int rl = i >> 7;
        const int j  = i & 127;
        const int y  = y0 + rl;
        float s = 0.0f;
        if (y >= 0 && y < 512) {
            const float* Ay = An + (size_t)y * 512;
            const int base = 4 * j;
            const vfloat4 m0 = *(const vfloat4*)(Ay + max(base - 4, 0));
            const vfloat4 m1 = *(const vfloat4*)(Ay + base);
            const vfloat4 m2 = *(const vfloat4*)(Ay + min(base + 4, 508));
            float e0 = m0.z, e1 = m0.w, e6 = m2.x, e7 = m2.y;
            if (j == 0)   { e0 = 0.0f; e1 = 0.0f; }
            if (j == 127) { e6 = 0.0f; e7 = 0.0f; }
            s = 0.125f * e0 + 0.375f * e1
              + 0.625f * m1.x + 0.875f * m1.y
              + 0.875f * m1.z + 0.625f * m1.w
              + 0.375f * e6 + 0.125f * e7;
            if (j == 0)   s += 0.375f * Ay[0]   + 0.125f * Ay[1];
            if (j == 127) s += 0.125f * Ay[510] + 0.375f * Ay[511];
        }
        b1loc[rl][j] = s;
    }
    __syncthreads();

    const float w[8] = {0.125f, 0.375f, 0.625f, 0.875f,
                        0.875f, 0.625f, 0.375f, 0.125f};
#pragma unroll
    for (int i = t; i < 512; i += 256) {
        const int tyl = i >> 7;
        const int j   = i & 127;
        const int ty  = tc * 4 + tyl;
        float s = 0.0f;
#pragma unroll
        for (int p = 0; p < 8; ++p)
            s = fmaf(w[p], b1loc[4 * tyl + p][j], s);
        if (ty == 0)   s += 0.375f * b1loc[2][j]  + 0.125f * b1loc[3][j];   // y=0,1
        if (ty == 127) s += 0.125f * b1loc[16][j] + 0.375f * b1loc[17][j];  // y=510,511
        B2[(size_t)nr * KTOT2 + ty * 128 + j] = s;
    }
}

// ---------------------------------------------------------------------------
// K2: za partials = B2 (20 x 16384) . x^T (64 x 16384).
// 256 blocks (64 kc x 4 batch-quarters) x 512 thr — full CU coverage, no LDS.
// Wave handles 2 batches; 4-value exchange tree; lanes 0-3 store.
// ---------------------------------------------------------------------------
__global__ __launch_bounds__(512) void za_partial_kernel(
    const float* __restrict__ x,      // (64, 16384)
    const float* __restrict__ B2,     // (20, 16384)
    float* __restrict__ partial)      // (64, 1280) elem b*20+nr
{
    const int t    = threadIdx.x;
    const int kc   = blockIdx.x >> 2; // 0..63
    const int bq   = blockIdx.x & 3;  // 0..3
    const int wv   = t >> 6;
    const int lane = t & 63;
    const int b0   = bq * 16 + wv * 2;
    const size_t kbase = (size_t)kc * 256 + 4 * lane;

    vfloat4 xv0 = *(const vfloat4*)(x + (size_t)b0 * KTOT2 + kbase);
    vfloat4 xv1 = *(const vfloat4*)(x + (size_t)(b0 + 1) * KTOT2 + kbase);

    float* pb = partial + (size_t)kc * 1280;
    const int lane1 = lane & 1, lane2 = lane & 2;

#pragma unroll
    for (int ch = 0; ch < 2; ++ch) {
        float acc[4][5];              // [bi*2+par][tt]
#pragma unroll
        for (int v = 0; v < 4; ++v)
#pragma unroll
            for (int tt = 0; tt < 5; ++tt) acc[v][tt] = 0.0f;

#pragma unroll
        for (int tt = 0; tt < 5; ++tt)
#pragma unroll
            for (int par = 0; par < 2; ++par) {
                const int nr = ch * 10 + 2 * tt + par;
                const vfloat4 bq4 = *(const vfloat4*)(B2 + (size_t)nr * KTOT2 + kbase);
                acc[par][tt] =
                    fmaf(bq4.x, xv0.x, fmaf(bq4.y, xv0.y,
                    fmaf(bq4.z, xv0.z, fmaf(bq4.w, xv0.w, acc[par][tt]))));
                acc[2 + par][tt] =
                    fmaf(bq4.x, xv1.x, fmaf(bq4.y, xv1.y,
                    fmaf(bq4.z, xv1.z, fmaf(bq4.w, xv1.w, acc[2 + par][tt]))));
            }

        // stage1: pair (v, v+2) on lane bit0 -> value-bit "bi" = lane bit0
        float s1[2][5];
#pragma unroll
        for (int v = 0; v < 2; ++v)
#pragma unroll
            for (int tt = 0; tt < 5; ++tt) {
                const float u = acc[v][tt], h = acc[v + 2][tt];
                s1[v][tt] = (lane1 ? h : u) + swz_x1(lane1 ? u : h);
            }
        // stage2: pair (0,1) on lane bit1 -> value-bit "par" = lane bit1
        float s2[5];
#pragma unroll
        for (int tt = 0; tt < 5; ++tt) {
            const float u = s1[0][tt], h = s1[1][tt];
            s2[tt] = (lane2 ? h : u) + swz_x2(lane2 ? u : h);
        }
        // butterfly over remaining lane bits 2..5
#pragma unroll
        for (int tt = 0; tt < 5; ++tt) {
            s2[tt] += swz_x4(s2[tt]);
            s2[tt] += swz_x8(s2[tt]);
            s2[tt] += __shfl_xor(s2[tt], 16, 64);
            s2[tt] += __shfl_xor(s2[tt], 32, 64);
        }

        // lanes 0-3 hold value m: bi = lane&1, par = (lane&2)>>1
        if (lane < 4) {
            const int bi  = lane & 1;
            const int par = (lane >> 1) & 1;
            float* dst = pb + (size_t)(b0 + bi) * 20 + ch * 10 + par;
#pragma unroll
            for (int tt = 0; tt < 5; ++tt) dst[2 * tt] = s2[tt];
        }
    }
}

// ---------------------------------------------------------------------------
// K3: za[c] = sum over 64 k-chunk partials. 5 blocks x 256 thr, coalesced.
// ---------------------------------------------------------------------------
__global__ __launch_bounds__(256) void za_reduce_kernel(
    const float* __restrict__ partial, float* __restrict__ za)
{
    const int c = blockIdx.x * 256 + threadIdx.x;
    float a0 = 0, a1 = 0, a2 = 0, a3 = 0;
    for (int r = 0; r < NKC; r += 4) {
        a0 += partial[(size_t)(r + 0) * 1280 + c];
        a1 += partial[(size_t)(r + 1) * 1280 + c];
        a2 += partial[(size_t)(r + 2) * 1280 + c];
        a3 += partial[(size_t)(r + 3) * 1280 + c];
    }
    za[c] = (a0 + a1) + (a2 + a3);
}

// ---------------------------------------------------------------------------
// K4: z recurrence (from za, per block — 5 KB L2-hot) + out = z*C^T + bias.
// 512 blocks = 256 s-chunks x 2 batch-halves; thread owns 4 consecutive s;
// float4 NT stores.
// ---------------------------------------------------------------------------
__global__ __launch_bounds__(256) void out_kernel(
    const float* __restrict__ C,      // (S,4)
    const float* __restrict__ bias,   // (S,)
    const float* __restrict__ za,     // (1280,) elem b*20+nr
    float* __restrict__ out)          // (64,S)
{
    __shared__ float zs[256];
    const int t = threadIdx.x;
    if (t < 64) {
#pragma unroll
        for (int r = 0; r < 4; ++r) {
            float zv = za[t * 20 + r];                  // n = 0
#pragma unroll
            for (int n = 1; n < 5; ++n)
                zv *= (1.0f + za[t * 20 + n * 4 + r]);
            zs[t * 4 + r] = zv;
        }
    }
    __syncthreads();

    const int sb = blockIdx.x >> 1;
    const int bh = blockIdx.x & 1;
    const int s0 = (sb * 256 + t) * 4;
    const vfloat4 c0 = *(const vfloat4*)(C + (size_t)s0 * 4);
    const vfloat4 c1 = *(const vfloat4*)(C + (size_t)s0 * 4 + 4);
    const vfloat4 c2 = *(const vfloat4*)(C + (size_t)s0 * 4 + 8);
    const vfloat4 c3 = *(const vfloat4*)(C + (size_t)s0 * 4 + 12);
    const vfloat4 bv = *(const vfloat4*)(bias + s0);

#pragma unroll 8
    for (int bb = bh * 32; bb < bh * 32 + 32; ++bb) {
        const float z0 = zs[bb * 4 + 0], z1 = zs[bb * 4 + 1];
        const float z2 = zs[bb * 4 + 2], z3 = zs[bb * 4 + 3];
        vfloat4 o;
        o.x = fmaf(z0, c0.x, fmaf(z1, c0.y, fmaf(z2, c0.z, fmaf(z3, c0.w, bv.x))));
        o.y = fmaf(z0, c1.x, fmaf(z1, c1.y, fmaf(z2, c1.z, fmaf(z3, c1.w, bv.y))));
        o.z = fmaf(z0, c2.x, fmaf(z1, c2.y, fmaf(z2, c2.z, fmaf(z3, c2.w, bv.z))));
        o.w = fmaf(z0, c3.x, fmaf(z1, c3.y, fmaf(z2, c3.z, fmaf(z3, c3.w, bv.w))));
        __builtin_nontemporal_store(o, (vfloat4*)(out + (size_t)bb * S_TOTAL + s0));
    }
}

// ---------------------------------------------------------------------------
extern "C" void kernel_launch(void* const* d_in, const int* in_sizes, int n_in,
                              void* d_out, int out_size, void* d_ws, size_t ws_size,
                              hipStream_t stream)
{
    const float* x    = (const float*)d_in[0];
    const float* A    = (const float*)d_in[1];
    const float* C    = (const float*)d_in[2];
    const float* bias = (const float*)d_in[3];
    float* out = (float*)d_out;

    float* B2      = (float*)d_ws;                        // 20*16384 = 1.31 MB
    float* partial = B2 + (size_t)20 * KTOT2;             // 64*1280
    float* za      = partial + (size_t)NKC * 1280;        // 1280

    adjxy_kernel<<<640, 256, 0, stream>>>(A, B2);
    za_partial_kernel<<<256, 512, 0, stream>>>(x, B2, partial);
    za_reduce_kernel<<<5, 256, 0, stream>>>(partial, za);
    out_kernel<<<512, 256, 0, stream>>>(C, bias, za, out);
}

// Round 12
// 33.274 us; speedup vs baseline: 2.6961x; 1.0499x over previous
//
#include <hip/hip_runtime.h>

#define S_TOTAL (512 * 512)     // 262144
#define BATCH 64
#define KTOT2 16384             // 128 ty * 128 j  (fully folded K)
#define NPR 16                  // partial rows (kc4 chunks)

typedef float vfloat4 __attribute__((ext_vector_type(4)));

// ds_swizzle xor helpers (imm must be literal). BitMode: (xor<<10)|0x1f.
__device__ __forceinline__ float swz_x1(float v) {
    return __int_as_float(__builtin_amdgcn_ds_swizzle(__float_as_int(v), 0x041F));
}
__device__ __forceinline__ float swz_x2(float v) {
    return __int_as_float(__builtin_amdgcn_ds_swizzle(__float_as_int(v), 0x081F));
}
__device__ __forceinline__ float swz_x4(float v) {
    return __int_as_float(__builtin_amdgcn_ds_swizzle(__float_as_int(v), 0x101F));
}
__device__ __forceinline__ float swz_x8(float v) {
    return __int_as_float(__builtin_amdgcn_ds_swizzle(__float_as_int(v), 0x201F));
}

// ---------------------------------------------------------------------------
// K1: A -> B2 (both bilinear adjoints folded). 640 blocks x 256 thr.
// Unchanged from R11 (proven, absmax 0.5).
// ---------------------------------------------------------------------------
__global__ __launch_bounds__(256) void adjxy_kernel(
    const float* __restrict__ A,      // (20, 512, 512)
    float* __restrict__ B2)           // (20, 128, 128)
{
    __shared__ float b1loc[20][128];  // 10 KB

    const int t  = threadIdx.x;
    const int nr = blockIdx.x >> 5;   // 0..19
    const int tc = blockIdx.x & 31;   // ty-chunk 0..31
    const int y0 = 16 * tc - 2;       // global y of local row 0

    const float* An = A + (size_t)nr * S_TOTAL;

#pragma unroll
    for (int i = t; i < 20 * 128; i += 256) {
        const int rl = i >> 7;
        const int j  = i & 127;
        const int y  = y0 + rl;
        float s = 0.0f;
        if (y >= 0 && y < 512) {
            const float* Ay = An + (size_t)y * 512;
            const int base = 4 * j;
            const vfloat4 m0 = *(const vfloat4*)(Ay + max(base - 4, 0));
            const vfloat4 m1 = *(const vfloat4*)(Ay + base);
            const vfloat4 m2 = *(const vfloat4*)(Ay + min(base + 4, 508));
            float e0 = m0.z, e1 = m0.w, e6 = m2.x, e7 = m2.y;
            if (j == 0)   { e0 = 0.0f; e1 = 0.0f; }
            if (j == 127) { e6 = 0.0f; e7 = 0.0f; }
            s = 0.125f * e0 + 0.375f * e1
              + 0.625f * m1.x + 0.875f * m1.y
              + 0.875f * m1.z + 0.625f * m1.w
              + 0.375f * e6 + 0.125f * e7;
            if (j == 0)   s += 0.375f * Ay[0]   + 0.125f * Ay[1];
            if (j == 127) s += 0.125f * Ay[510] + 0.375f * Ay[511];
        }
        b1loc[rl][j] = s;
    }
    __syncthreads();

    const float w[8] = {0.125f, 0.375f, 0.625f, 0.875f,
                        0.875f, 0.625f, 0.375f, 0.125f};
#pragma unroll
    for (int i = t; i < 512; i += 256) {
        const int tyl = i >> 7;
        const int j   = i & 127;
        const int ty  = tc * 4 + tyl;
        float s = 0.0f;
#pragma unroll
        for (int p = 0; p < 8; ++p)
            s = fmaf(w[p], b1loc[4 * tyl + p][j], s);
        if (ty == 0)   s += 0.375f * b1loc[2][j]  + 0.125f * b1loc[3][j];   // y=0,1
        if (ty == 127) s += 0.125f * b1loc[16][j] + 0.375f * b1loc[17][j];  // y=510,511
        B2[(size_t)nr * KTOT2 + ty * 128 + j] = s;
    }
}

// ---------------------------------------------------------------------------
// K2: za partials, 16 rows. 256 blocks (16 kc4 x 16 bq, 4 batches) x 512 thr.
// Wave (kcl 0..3, bh 0..1) runs the R11-proven per-wave path (2 batches,
// 256-k slice, halving tree); LDS red[4][80] sums the 4 kcl-waves.
// ---------------------------------------------------------------------------
__global__ __launch_bounds__(512) void za_partial_kernel(
    const float* __restrict__ x,      // (64, 16384)
    const float* __restrict__ B2,     // (20, 16384)
    float* __restrict__ partial)      // (16, 1280) elem b*20+nr
{
    __shared__ float red[4][80];      // [kcl][b_local*20+nr]

    const int t    = threadIdx.x;
    const int kc4  = blockIdx.x >> 4; // 0..15
    const int bqn  = blockIdx.x & 15; // 0..15
    const int wv   = t >> 6;
    const int lane = t & 63;
    const int kcl  = wv & 3;          // k sub-chunk within kc4
    const int bh   = wv >> 2;         // batch half of the 4
    const int kc   = kc4 * 4 + kcl;   // 0..63
    const int b0   = bqn * 4 + bh * 2;
    const size_t kbase = (size_t)kc * 256 + 4 * lane;

    const vfloat4 xv0 = *(const vfloat4*)(x + (size_t)b0 * KTOT2 + kbase);
    const vfloat4 xv1 = *(const vfloat4*)(x + (size_t)(b0 + 1) * KTOT2 + kbase);

    const int lane1 = lane & 1, lane2 = lane & 2;

#pragma unroll
    for (int ch = 0; ch < 2; ++ch) {
        float acc[4][5];              // [bi*2+par][tt]
#pragma unroll
        for (int v = 0; v < 4; ++v)
#pragma unroll
            for (int tt = 0; tt < 5; ++tt) acc[v][tt] = 0.0f;

#pragma unroll
        for (int tt = 0; tt < 5; ++tt)
#pragma unroll
            for (int par = 0; par < 2; ++par) {
                const int nr = ch * 10 + 2 * tt + par;
                const vfloat4 bq4 = *(const vfloat4*)(B2 + (size_t)nr * KTOT2 + kbase);
                acc[par][tt] =
                    fmaf(bq4.x, xv0.x, fmaf(bq4.y, xv0.y,
                    fmaf(bq4.z, xv0.z, fmaf(bq4.w, xv0.w, acc[par][tt]))));
                acc[2 + par][tt] =
                    fmaf(bq4.x, xv1.x, fmaf(bq4.y, xv1.y,
                    fmaf(bq4.z, xv1.z, fmaf(bq4.w, xv1.w, acc[2 + par][tt]))));
            }

        // stage1: value-bit "bi" <- lane bit0
        float s1[2][5];
#pragma unroll
        for (int v = 0; v < 2; ++v)
#pragma unroll
            for (int tt = 0; tt < 5; ++tt) {
                const float u = acc[v][tt], h = acc[v + 2][tt];
                s1[v][tt] = (lane1 ? h : u) + swz_x1(lane1 ? u : h);
            }
        // stage2: value-bit "par" <- lane bit1
        float s2[5];
#pragma unroll
        for (int tt = 0; tt < 5; ++tt) {
            const float u = s1[0][tt], h = s1[1][tt];
            s2[tt] = (lane2 ? h : u) + swz_x2(lane2 ? u : h);
        }
        // butterfly over remaining lane bits 2..5
#pragma unroll
        for (int tt = 0; tt < 5; ++tt) {
            s2[tt] += swz_x4(s2[tt]);
            s2[tt] += swz_x8(s2[tt]);
            s2[tt] += __shfl_xor(s2[tt], 16, 64);
            s2[tt] += __shfl_xor(s2[tt], 32, 64);
        }

        // lanes 0-3: bi = lane&1, par = (lane>>1)&1  (R11-proven mapping)
        if (lane < 4) {
            const int bi  = lane & 1;
            const int par = (lane >> 1) & 1;
#pragma unroll
            for (int tt = 0; tt < 5; ++tt)
                red[kcl][(bh * 2 + bi) * 20 + ch * 10 + 2 * tt + par] = s2[tt];
        }
    }

    __syncthreads();
    if (t < 80) {
        const float s = red[0][t] + red[1][t] + red[2][t] + red[3][t];
        const int bl = t / 20;
        const int nr = t - bl * 20;
        partial[(size_t)kc4 * 1280 + (bqn * 4 + bl) * 20 + nr] = s;
    }
}

// ---------------------------------------------------------------------------
// K3: per-block 16-row za reduce (80 KB L2-hot, coalesced) + z recurrence +
// out = z*C^T + bias. 512 blocks = 256 s-chunks x 2 batch-halves; thread owns
// 4 consecutive s; float4 NT stores.
// ---------------------------------------------------------------------------
__global__ __launch_bounds__(256) void out_kernel(
    const float* __restrict__ C,       // (S,4)
    const float* __restrict__ bias,    // (S,)
    const float* __restrict__ partial, // (16, 1280)
    float* __restrict__ out)           // (64,S)
{
    __shared__ float za_sh[1280];
    __shared__ float zs[256];
    const int t = threadIdx.x;

    const int sb = blockIdx.x >> 1;
    const int bh = blockIdx.x & 1;
    const int s0 = (sb * 256 + t) * 4;
    // issue the streaming-phase loads first so they overlap the reduce
    const vfloat4 c0 = *(const vfloat4*)(C + (size_t)s0 * 4);
    const vfloat4 c1 = *(const vfloat4*)(C + (size_t)s0 * 4 + 4);
    const vfloat4 c2 = *(const vfloat4*)(C + (size_t)s0 * 4 + 8);
    const vfloat4 c3 = *(const vfloat4*)(C + (size_t)s0 * 4 + 12);
    const vfloat4 bv = *(const vfloat4*)(bias + s0);

    // 16-row reduce, coalesced columns
#pragma unroll
    for (int q = 0; q < 5; ++q) {
        const int c = q * 256 + t;
        float a0 = 0, a1 = 0, a2 = 0, a3 = 0;
#pragma unroll
        for (int r = 0; r < NPR; r += 4) {
            a0 += partial[(size_t)(r + 0) * 1280 + c];
            a1 += partial[(size_t)(r + 1) * 1280 + c];
            a2 += partial[(size_t)(r + 2) * 1280 + c];
            a3 += partial[(size_t)(r + 3) * 1280 + c];
        }
        za_sh[c] = (a0 + a1) + (a2 + a3);
    }
    __syncthreads();
    if (t < 64) {
#pragma unroll
        for (int r = 0; r < 4; ++r) {
            float zv = za_sh[t * 20 + r];               // n = 0
#pragma unroll
            for (int n = 1; n < 5; ++n)
                zv *= (1.0f + za_sh[t * 20 + n * 4 + r]);
            zs[t * 4 + r] = zv;
        }
    }
    __syncthreads();

#pragma unroll 8
    for (int bb = bh * 32; bb < bh * 32 + 32; ++bb) {
        const float z0 = zs[bb * 4 + 0], z1 = zs[bb * 4 + 1];
        const float z2 = zs[bb * 4 + 2], z3 = zs[bb * 4 + 3];
        vfloat4 o;
        o.x = fmaf(z0, c0.x, fmaf(z1, c0.y, fmaf(z2, c0.z, fmaf(z3, c0.w, bv.x))));
        o.y = fmaf(z0, c1.x, fmaf(z1, c1.y, fmaf(z2, c1.z, fmaf(z3, c1.w, bv.y))));
        o.z = fmaf(z0, c2.x, fmaf(z1, c2.y, fmaf(z2, c2.z, fmaf(z3, c2.w, bv.z))));
        o.w = fmaf(z0, c3.x, fmaf(z1, c3.y, fmaf(z2, c3.z, fmaf(z3, c3.w, bv.w))));
        __builtin_nontemporal_store(o, (vfloat4*)(out + (size_t)bb * S_TOTAL + s0));
    }
}

// ---------------------------------------------------------------------------
extern "C" void kernel_launch(void* const* d_in, const int* in_sizes, int n_in,
                              void* d_out, int out_size, void* d_ws, size_t ws_size,
                              hipStream_t stream)
{
    const float* x    = (const float*)d_in[0];
    const float* A    = (const float*)d_in[1];
    const float* C    = (const float*)d_in[2];
    const float* bias = (const float*)d_in[3];
    float* out = (float*)d_out;

    float* B2      = (float*)d_ws;                        // 20*16384 = 1.31 MB
    float* partial = B2 + (size_t)20 * KTOT2;             // 16*1280 = 80 KB

    adjxy_kernel<<<640, 256, 0, stream>>>(A, B2);
    za_partial_kernel<<<256, 512, 0, stream>>>(x, B2, partial);
    out_kernel<<<512, 256, 0, stream>>>(C, bias, partial, out);
}

// Round 13
// 31.317 us; speedup vs baseline: 2.8646x; 1.0625x over previous
//
#include <hip/hip_runtime.h>

#define S_TOTAL (512 * 512)     // 262144
#define BATCH 64
#define NPR 16                  // partial rows (tcp chunks)

typedef float vfloat4 __attribute__((ext_vector_type(4)));

// ds_swizzle xor helpers (imm must be literal). BitMode: (xor<<10)|0x1f.
__device__ __forceinline__ float swz_x1(float v) {
    return __int_as_float(__builtin_amdgcn_ds_swizzle(__float_as_int(v), 0x041F));
}
__device__ __forceinline__ float swz_x2(float v) {
    return __int_as_float(__builtin_amdgcn_ds_swizzle(__float_as_int(v), 0x081F));
}
__device__ __forceinline__ float swz_x4(float v) {
    return __int_as_float(__builtin_amdgcn_ds_swizzle(__float_as_int(v), 0x101F));
}
__device__ __forceinline__ float swz_x8(float v) {
    return __int_as_float(__builtin_amdgcn_ds_swizzle(__float_as_int(v), 0x201F));
}

// ---------------------------------------------------------------------------
// K1 (fused, lean): block = (nr 0..19, tcp 0..15).  Covers ty rows
// 8*tcp..8*tcp+7 (1024 k) of ONE nr.
//   phase 1: x-fold straight from global (proven R12 3-window pattern),
//            36-row y-window, zero-pad y outside [0,512)  -> b1loc (18 KB)
//   phase 2: y-fold -> b2loc[1024] (4 KB)   [proven R12 tap/edge structure]
//   phase 3: dot with x (8 waves x 8 batches, 4 k-quads/lane), 3-stage
//            halving tree + 3 butterflies -> partial[tcp][b*20+nr]
// blockIdx XCD-pinned: tcp%8 == blk%8 so the 20 nr-blocks sharing a tcp's
// x-slice hit the same XCD L2.  LDS 22 KB, 512 thr -> no occupancy cliff.
// ---------------------------------------------------------------------------
__global__ __launch_bounds__(512) void fused_za_kernel(
    const float* __restrict__ x,      // (64, 16384)
    const float* __restrict__ A,      // (20, 512, 512)
    float* __restrict__ partial)      // (16, 1280) elem b*20+nr
{
    __shared__ float b1loc[36][128];  // 18 KB
    __shared__ float b2loc[1024];     // 4 KB

    const int t   = threadIdx.x;
    const int blk = blockIdx.x;
    // XCD-pinned decode: tcp = (q/20)*8 + (blk&7), nr = q%20, q = blk>>3
    const int q   = blk >> 3;
    const int nr  = q % 20;
    const int tcp = (q / 20) * 8 + (blk & 7);
    const int y0  = 32 * tcp - 2;     // global y of local row 0

    const float* An = A + (size_t)nr * S_TOTAL;

    // ---- phase 1: x-fold (36 rows x 128 j)
#pragma unroll 3
    for (int i = t; i < 36 * 128; i += 512) {
        const int rl = i >> 7;
        const int j  = i & 127;
        const int y  = y0 + rl;
        float s = 0.0f;
        if (y >= 0 && y < 512) {
            const float* Ay = An + (size_t)y * 512;
            const int base = 4 * j;
            const vfloat4 m0 = *(const vfloat4*)(Ay + max(base - 4, 0));
            const vfloat4 m1 = *(const vfloat4*)(Ay + base);
            const vfloat4 m2 = *(const vfloat4*)(Ay + min(base + 4, 508));
            float e0 = m0.z, e1 = m0.w, e6 = m2.x, e7 = m2.y;
            if (j == 0)   { e0 = 0.0f; e1 = 0.0f; }
            if (j == 127) { e6 = 0.0f; e7 = 0.0f; }
            s = 0.125f * e0 + 0.375f * e1
              + 0.625f * m1.x + 0.875f * m1.y
              + 0.875f * m1.z + 0.625f * m1.w
              + 0.375f * e6 + 0.125f * e7;
            if (j == 0)   s += 0.375f * Ay[0]   + 0.125f * Ay[1];
            if (j == 127) s += 0.125f * Ay[510] + 0.375f * Ay[511];
        }
        b1loc[rl][j] = s;
    }
    __syncthreads();

    // ---- phase 2: y-fold (8 ty x 128 j) -> b2loc[kl = tyl*128 + j]
    const float w[8] = {0.125f, 0.375f, 0.625f, 0.875f,
                        0.875f, 0.625f, 0.375f, 0.125f};
#pragma unroll
    for (int i = t; i < 1024; i += 512) {
        const int tyl = i >> 7;
        const int j   = i & 127;
        const int ty  = tcp * 8 + tyl;
        float s = 0.0f;
#pragma unroll
        for (int p = 0; p < 8; ++p)
            s = fmaf(w[p], b1loc[4 * tyl + p][j], s);
        if (ty == 0)   s += 0.375f * b1loc[2][j]  + 0.125f * b1loc[3][j];   // y=0,1 (rl 2,3)
        if (ty == 127) s += 0.125f * b1loc[32][j] + 0.375f * b1loc[33][j];  // y=510,511 (rl 32,33)
        b2loc[i] = s;
    }
    __syncthreads();

    // ---- phase 3: dot with x.  wave wv handles batches 8*wv..8*wv+7.
    const int wv   = t >> 6;
    const int lane = t & 63;
    const int b0   = wv * 8;
    const size_t xbase = (size_t)tcp * 1024 + 4 * lane;

    // b2 quads (LDS, conflict-free b128)
    vfloat4 bq0 = *(const vfloat4*)&b2loc[4 * lane];
    vfloat4 bq1 = *(const vfloat4*)&b2loc[4 * lane + 256];
    vfloat4 bq2 = *(const vfloat4*)&b2loc[4 * lane + 512];
    vfloat4 bq3 = *(const vfloat4*)&b2loc[4 * lane + 768];

    float acc[8];
#pragma unroll
    for (int bi = 0; bi < 8; ++bi) {
        const float* xb = x + (size_t)(b0 + bi) * 16384 + xbase;
        const vfloat4 x0 = *(const vfloat4*)(xb);
        const vfloat4 x1 = *(const vfloat4*)(xb + 256);
        const vfloat4 x2 = *(const vfloat4*)(xb + 512);
        const vfloat4 x3 = *(const vfloat4*)(xb + 768);
        float a = 0.0f;
        a = fmaf(bq0.x, x0.x, fmaf(bq0.y, x0.y, fmaf(bq0.z, x0.z, fmaf(bq0.w, x0.w, a))));
        a = fmaf(bq1.x, x1.x, fmaf(bq1.y, x1.y, fmaf(bq1.z, x1.z, fmaf(bq1.w, x1.w, a))));
        a = fmaf(bq2.x, x2.x, fmaf(bq2.y, x2.y, fmaf(bq2.z, x2.z, fmaf(bq2.w, x2.w, a))));
        a = fmaf(bq3.x, x3.x, fmaf(bq3.y, x3.y, fmaf(bq3.z, x3.z, fmaf(bq3.w, x3.w, a))));
        acc[bi] = a;
    }

    // halving tree: 8 values over lane bits 0..2, butterfly bits 3..5
    const int lane1 = lane & 1, lane2 = lane & 2, lane4 = lane & 4;
    float s1[4];
#pragma unroll
    for (int v = 0; v < 4; ++v) {
        const float u = acc[v], h = acc[v + 4];
        s1[v] = (lane1 ? h : u) + swz_x1(lane1 ? u : h);
    }
    float s2[2];
#pragma unroll
    for (int v = 0; v < 2; ++v) {
        const float u = s1[v], h = s1[v + 2];
        s2[v] = (lane2 ? h : u) + swz_x2(lane2 ? u : h);
    }
    float s3;
    {
        const float u = s2[0], h = s2[1];
        s3 = (lane4 ? h : u) + swz_x4(lane4 ? u : h);
    }
    s3 += swz_x8(s3);
    s3 += __shfl_xor(s3, 16, 64);
    s3 += __shfl_xor(s3, 32, 64);

    // lanes 0-7 hold value m = rev3(lane): bit2=lane0, bit1=lane1, bit0=lane2
    if (lane < 8) {
        const int m = ((lane & 1) << 2) | (lane & 2) | ((lane & 4) >> 2);
        partial[(size_t)tcp * 1280 + (b0 + m) * 20 + nr] = s3;
    }
}

// ---------------------------------------------------------------------------
// K2: per-block 16-row za reduce (80 KB L2-hot, coalesced) + z recurrence +
// out = z*C^T + bias. 512 blocks = 256 s-chunks x 2 batch-halves; thread owns
// 4 consecutive s; float4 NT stores.  Unchanged from R12 (proven).
// ---------------------------------------------------------------------------
__global__ __launch_bounds__(256) void out_kernel(
    const float* __restrict__ C,       // (S,4)
    const float* __restrict__ bias,    // (S,)
    const float* __restrict__ partial, // (16, 1280)
    float* __restrict__ out)           // (64,S)
{
    __shared__ float za_sh[1280];
    __shared__ float zs[256];
    const int t = threadIdx.x;

    const int sb = blockIdx.x >> 1;
    const int bh = blockIdx.x & 1;
    const int s0 = (sb * 256 + t) * 4;
    const vfloat4 c0 = *(const vfloat4*)(C + (size_t)s0 * 4);
    const vfloat4 c1 = *(const vfloat4*)(C + (size_t)s0 * 4 + 4);
    const vfloat4 c2 = *(const vfloat4*)(C + (size_t)s0 * 4 + 8);
    const vfloat4 c3 = *(const vfloat4*)(C + (size_t)s0 * 4 + 12);
    const vfloat4 bv = *(const vfloat4*)(bias + s0);

#pragma unroll
    for (int qq = 0; qq < 5; ++qq) {
        const int c = qq * 256 + t;
        float a0 = 0, a1 = 0, a2 = 0, a3 = 0;
#pragma unroll
        for (int r = 0; r < NPR; r += 4) {
            a0 += partial[(size_t)(r + 0) * 1280 + c];
            a1 += partial[(size_t)(r + 1) * 1280 + c];
            a2 += partial[(size_t)(r + 2) * 1280 + c];
            a3 += partial[(size_t)(r + 3) * 1280 + c];
        }
        za_sh[c] = (a0 + a1) + (a2 + a3);
    }
    __syncthreads();
    if (t < 64) {
#pragma unroll
        for (int r = 0; r < 4; ++r) {
            float zv = za_sh[t * 20 + r];               // n = 0
#pragma unroll
            for (int n = 1; n < 5; ++n)
                zv *= (1.0f + za_sh[t * 20 + n * 4 + r]);
            zs[t * 4 + r] = zv;
        }
    }
    __syncthreads();

#pragma unroll 8
    for (int bb = bh * 32; bb < bh * 32 + 32; ++bb) {
        const float z0 = zs[bb * 4 + 0], z1 = zs[bb * 4 + 1];
        const float z2 = zs[bb * 4 + 2], z3 = zs[bb * 4 + 3];
        vfloat4 o;
        o.x = fmaf(z0, c0.x, fmaf(z1, c0.y, fmaf(z2, c0.z, fmaf(z3, c0.w, bv.x))));
        o.y = fmaf(z0, c1.x, fmaf(z1, c1.y, fmaf(z2, c1.z, fmaf(z3, c1.w, bv.y))));
        o.z = fmaf(z0, c2.x, fmaf(z1, c2.y, fmaf(z2, c2.z, fmaf(z3, c2.w, bv.z))));
        o.w = fmaf(z0, c3.x, fmaf(z1, c3.y, fmaf(z2, c3.z, fmaf(z3, c3.w, bv.w))));
        __builtin_nontemporal_store(o, (vfloat4*)(out + (size_t)bb * S_TOTAL + s0));
    }
}

// ---------------------------------------------------------------------------
extern "C" void kernel_launch(void* const* d_in, const int* in_sizes, int n_in,
                              void* d_out, int out_size, void* d_ws, size_t ws_size,
                              hipStream_t stream)
{
    const float* x    = (const float*)d_in[0];
    const float* A    = (const float*)d_in[1];
    const float* C    = (const float*)d_in[2];
    const float* bias = (const float*)d_in[3];
    float* out = (float*)d_out;

    float* partial = (float*)d_ws;                        // 16*1280 = 80 KB

    fused_za_kernel<<<320, 512, 0, stream>>>(x, A, partial);
    out_kernel<<<512, 256, 0, stream>>>(C, bias, partial, out);
}